// Round 7
// baseline (46.720 us; speedup 1.0000x reference)
//
#include <hip/hip_runtime.h>

// SKA: out[n, g*CW+cw, h, w] = sum_{a,b in 0..2} x[n, g*CW+cw, h+a-1, w+b-1] * w[n, cw, a*3+b, h, w]
// x: (8, 256, 96, 96) f32 ; w: (8, 32, 9, 96, 96) f32 ; out: (8, 256, 96, 96) f32
// Round 6: force memory-level parallelism. R5's xm[8] batch was re-sunk by the
// compiler (VGPR=60 => ~2 loads in flight). Pin load batches with
// sched_barrier(0) fences and software-pipeline the 3 window rows:
//   load row0+row1 (16 dwordx4 in flight) -> compute row0 -> load row2 ->
//   compute row1 -> compute row2.
// w taps are single-use -> nontemporal loads; out single-write -> NT stores.

#define N_  8
#define C_  256
#define H_  96
#define W_  96
#define CW_ 32
#define G_  8

typedef float f32x4 __attribute__((ext_vector_type(4)));

#define COMPUTE(A, XM)                                                        \
    {                                                                         \
        const f32x4 wa = wv[(A) * 3 + 0];                                     \
        const f32x4 wb_ = wv[(A) * 3 + 1];                                    \
        const f32x4 wc = wv[(A) * 3 + 2];                                     \
        _Pragma("unroll")                                                     \
        for (int g = 0; g < G_; ++g) {                                        \
            float xl = __shfl(XM[g].w, lane - 1);                             \
            float xr = __shfl(XM[g].x, lane + 1);                             \
            xl = (widx == 0) ? 0.f : xl;                                      \
            xr = (widx == 23) ? 0.f : xr;                                     \
            acc[g].x = fmaf(xl,       wa.x, acc[g].x);                        \
            acc[g].x = fmaf(XM[g].x,  wb_.x, acc[g].x);                       \
            acc[g].x = fmaf(XM[g].y,  wc.x, acc[g].x);                        \
            acc[g].y = fmaf(XM[g].x,  wa.y, acc[g].y);                        \
            acc[g].y = fmaf(XM[g].y,  wb_.y, acc[g].y);                       \
            acc[g].y = fmaf(XM[g].z,  wc.y, acc[g].y);                        \
            acc[g].z = fmaf(XM[g].y,  wa.z, acc[g].z);                        \
            acc[g].z = fmaf(XM[g].z,  wb_.z, acc[g].z);                       \
            acc[g].z = fmaf(XM[g].w,  wc.z, acc[g].z);                        \
            acc[g].w = fmaf(XM[g].z,  wa.w, acc[g].w);                        \
            acc[g].w = fmaf(XM[g].w,  wb_.w, acc[g].w);                       \
            acc[g].w = fmaf(xr,       wc.w, acc[g].w);                        \
        }                                                                     \
    }

__global__ __launch_bounds__(256, 3) void SKA_kernel(const float* __restrict__ x,
                                                     const float* __restrict__ wgt,
                                                     float* __restrict__ out) {
    constexpr size_t PLANE = (size_t)H_ * W_;  // 9216

    const int tid   = threadIdx.x;
    const int widx  = tid & 31;   // 0..31, 24 active
    const int rowid = tid >> 5;   // 0..7
    const int lane  = tid & 63;

    const int blk = blockIdx.x;
    const int ht  = blk % (H_ / 8);
    const int t1  = blk / (H_ / 8);
    const int cw  = t1 % CW_;
    const int n   = t1 / CW_;
    const int h   = ht * 8 + rowid;
    const int w0  = widx * 4;

    if (widx >= 24) return;

    // ---- 9 per-pixel kernel taps (single-use -> non-temporal) ----
    const float* wb = wgt + (((size_t)(n * CW_ + cw) * 9) * H_ + (size_t)h) * W_ + w0;
    f32x4 wv[9];
#pragma unroll
    for (int k = 0; k < 9; ++k)
        wv[k] = __builtin_nontemporal_load(
            reinterpret_cast<const f32x4*>(wb + (size_t)k * PLANE));

    f32x4 acc[G_];
#pragma unroll
    for (int g = 0; g < G_; ++g) acc[g] = (f32x4)(0.f);

    const float* xb = x + ((size_t)n * C_ + cw) * PLANE + w0;

    const int hm1 = (h - 1 < 0) ? 0 : h - 1;          // clamped (compute skipped if OOB)
    const int hp1 = (h + 1 >= H_) ? H_ - 1 : h + 1;

    f32x4 xmA[G_], xmB[G_];

    // issue row (a=0) and row (a=1) batches back-to-back: 16 dwordx4 in flight
#pragma unroll
    for (int g = 0; g < G_; ++g)
        xmA[g] = *reinterpret_cast<const f32x4*>(
            xb + (size_t)(g * CW_) * PLANE + (size_t)hm1 * W_);
#pragma unroll
    for (int g = 0; g < G_; ++g)
        xmB[g] = *reinterpret_cast<const f32x4*>(
            xb + (size_t)(g * CW_) * PLANE + (size_t)h * W_);
    __builtin_amdgcn_sched_barrier(0);

    // compute a=0 (row h-1) while row-h and soon row-h+1 loads are in flight
    if (h > 0) COMPUTE(0, xmA)
    __builtin_amdgcn_sched_barrier(0);

    // issue row (a=2) batch, overwriting xmA
#pragma unroll
    for (int g = 0; g < G_; ++g)
        xmA[g] = *reinterpret_cast<const f32x4*>(
            xb + (size_t)(g * CW_) * PLANE + (size_t)hp1 * W_);
    __builtin_amdgcn_sched_barrier(0);

    // compute a=1 (row h, always valid)
    COMPUTE(1, xmB)
    __builtin_amdgcn_sched_barrier(0);

    // compute a=2 (row h+1)
    if (h < H_ - 1) COMPUTE(2, xmA)

    float* ob = out + ((size_t)n * C_ + cw) * PLANE + (size_t)h * W_ + w0;
#pragma unroll
    for (int g = 0; g < G_; ++g) {
        __builtin_nontemporal_store(
            acc[g], reinterpret_cast<f32x4*>(ob + (size_t)(g * CW_) * PLANE));
    }
}

extern "C" void kernel_launch(void* const* d_in, const int* in_sizes, int n_in,
                              void* d_out, int out_size, void* d_ws, size_t ws_size,
                              hipStream_t stream) {
    const float* x   = (const float*)d_in[0];
    const float* wgt = (const float*)d_in[1];
    float* out = (float*)d_out;

    constexpr int grid = N_ * CW_ * (H_ / 8);  // 3072 blocks x 256 threads
    SKA_kernel<<<grid, 256, 0, stream>>>(x, wgt, out);
}

// Round 8
// 43.911 us; speedup vs baseline: 1.0640x; 1.0640x over previous
//
#include <hip/hip_runtime.h>
#include <stdint.h>

// SKA: out[n, g*CW+cw, h, w] = sum_{a,b in 0..2} x[n, g*CW+cw, h+a-1, w+b-1] * w[n, cw, a*3+b, h, w]
// x: (8, 256, 96, 96) f32 ; w: (8, 32, 9, 96, 96) f32 ; out: (8, 256, 96, 96) f32
// Round 7: global_load_lds async staging. R5/R6 proved hipcc sinks VGPR loads
// (VGPR stuck at 60-64 => ~3 loads in flight, latency-bound at 3.9 TB/s eff).
// global_load_lds is fire-and-forget (no VGPR), 1 wave/block (no s_barrier),
// 12x dwordx4 staging + 9 w-tap loads all in flight, one vmcnt(0) sync.

#define N_  8
#define C_  256
#define H_  96
#define W_  96
#define CW_ 32
#define G_  8
#define PL_ (H_ * W_)  // 9216

typedef float f32x4 __attribute__((ext_vector_type(4)));

__global__ __launch_bounds__(64, 4) void SKA_kernel(const float* __restrict__ x,
                                                    const float* __restrict__ wgt,
                                                    float* __restrict__ out) {
    // x tile: [r:4][g:8][96 floats] = 3072 floats = 12 KiB (linear, global_load_lds dest)
    __shared__ float xs[4 * G_ * W_];

    const int lane  = threadIdx.x;  // 0..63 (one wave per block)
    const int widx  = lane & 31;    // 24 active per half-wave
    const int rowid = lane >> 5;    // 0..1

    // XCD-bijective swizzle: 12288 blocks = 8 XCDs x 1536; each XCD owns one n-image.
    const int b  = blockIdx.x;
    const int lb = (b & 7) * 1536 + (b >> 3);
    const int ht = lb % 48;
    const int t1 = lb / 48;
    const int cw = t1 % CW_;
    const int n  = t1 / CW_;
    const int h0 = ht * 2;
    const int h  = h0 + rowid;
    const int w0a = widx * 4;
    const int w0  = (w0a > W_ - 4) ? (W_ - 4) : w0a;  // clamped (lanes widx>=24 load junk in-bounds)
    const bool active = (widx < 24);

    // ---- issue 9 w-tap loads (register, single-use -> NT) ----
    const float* wb = wgt + (size_t)(((n * CW_ + cw) * 9) * H_ + h) * W_ + w0;
    f32x4 wv[9];
#pragma unroll
    for (int k = 0; k < 9; ++k)
        wv[k] = __builtin_nontemporal_load(reinterpret_cast<const f32x4*>(wb + k * PL_));

    // ---- issue 12 async global->LDS staging loads (no VGPR dest, all in flight) ----
    // chunk (r, cc): lane l covers floats [cc*256 + 4l .. +3] of row-slab r;
    // g = wo/96, col = wo%96 depend only on (cc, lane) -> 3 reusable patterns.
    const int nc = (n * C_ + cw) * PL_;
    int goff[3], csel[3];
#pragma unroll
    for (int cc = 0; cc < 3; ++cc) {
        const int wo = cc * 256 + lane * 4;
        goff[cc] = (wo / 96) * (CW_ * PL_);
        csel[cc] = wo % 96;
    }
#pragma unroll
    for (int r = 0; r < 4; ++r) {
        int row = h0 - 1 + r;
        row = row < 0 ? 0 : (row > H_ - 1 ? H_ - 1 : row);  // clamped; OOB rows never used
#pragma unroll
        for (int cc = 0; cc < 3; ++cc) {
            const int off = nc + goff[cc] + row * W_ + csel[cc];
            const uint32_t lds_off = (uint32_t)(uintptr_t)&xs[(r * 3 + cc) * 256];
            __builtin_amdgcn_global_load_lds(
                (const __attribute__((address_space(1))) void*)(uintptr_t)(x + off),
                (__attribute__((address_space(3))) void*)lds_off,
                16, 0, 0);
        }
    }

    // single-wave block: no s_barrier needed, just drain the VMEM queue
    __builtin_amdgcn_sched_barrier(0);
    asm volatile("s_waitcnt vmcnt(0)" ::: "memory");
    __builtin_amdgcn_sched_barrier(0);

    // ---- compute (R5-validated shfl-halo FMA chain, x from LDS) ----
    f32x4 acc[G_];
#pragma unroll
    for (int g = 0; g < G_; ++g) acc[g] = (f32x4)(0.f);

#pragma unroll
    for (int a = 0; a < 3; ++a) {
        const int hh = h + a - 1;
        if (hh < 0 || hh >= H_) continue;  // zero-pad rows (cross-half lanes masked below)
        const f32x4 wa = wv[a * 3 + 0];
        const f32x4 wm = wv[a * 3 + 1];
        const f32x4 wc = wv[a * 3 + 2];
#pragma unroll
        for (int g = 0; g < G_; ++g) {
            const f32x4 xm = *reinterpret_cast<const f32x4*>(
                &xs[(rowid + a) * (G_ * W_) + g * W_ + w0]);
            float xl = __shfl(xm.w, lane - 1);
            float xr = __shfl(xm.x, lane + 1);
            xl = (widx == 0) ? 0.f : xl;   // x[-1] pad
            xr = (widx == 23) ? 0.f : xr;  // x[96] pad
            acc[g].x = fmaf(xl,   wa.x, acc[g].x);
            acc[g].x = fmaf(xm.x, wm.x, acc[g].x);
            acc[g].x = fmaf(xm.y, wc.x, acc[g].x);
            acc[g].y = fmaf(xm.x, wa.y, acc[g].y);
            acc[g].y = fmaf(xm.y, wm.y, acc[g].y);
            acc[g].y = fmaf(xm.z, wc.y, acc[g].y);
            acc[g].z = fmaf(xm.y, wa.z, acc[g].z);
            acc[g].z = fmaf(xm.z, wm.z, acc[g].z);
            acc[g].z = fmaf(xm.w, wc.z, acc[g].z);
            acc[g].w = fmaf(xm.z, wa.w, acc[g].w);
            acc[g].w = fmaf(xm.w, wm.w, acc[g].w);
            acc[g].w = fmaf(xr,   wc.w, acc[g].w);
        }
    }

    if (active) {
        float* ob = out + nc + h * W_ + w0a;
#pragma unroll
        for (int g = 0; g < G_; ++g)
            __builtin_nontemporal_store(acc[g],
                reinterpret_cast<f32x4*>(ob + g * (CW_ * PL_)));
    }
}

extern "C" void kernel_launch(void* const* d_in, const int* in_sizes, int n_in,
                              void* d_out, int out_size, void* d_ws, size_t ws_size,
                              hipStream_t stream) {
    const float* x   = (const float*)d_in[0];
    const float* wgt = (const float*)d_in[1];
    float* out = (float*)d_out;

    constexpr int grid = N_ * CW_ * (H_ / 2);  // 12288 blocks x 64 threads
    SKA_kernel<<<grid, 64, 0, stream>>>(x, wgt, out);
}